// Round 5
// baseline (166.559 us; speedup 1.0000x reference)
//
#include <hip/hip_runtime.h>
#include <math.h>

#define NCOLS 65536
#define MROWS 256
#define NBINS 512
#define CHUNKS 8
#define CELEMS (NCOLS / CHUNKS)          // 8192 elements per chunk
#define TPB 512                          // 4 float4 per thread per array
#define ZLO 20.0f
#define INVW ((float)NBINS / (2.0f * ZLO))   // 12.8 bins per unit
#define BINW (2.0f * ZLO / (float)NBINS)     // 0.078125
#define PSCALE 8192.0f
#define CNT_SHIFT 40
#define POS_MASK ((1ull << CNT_SHIFT) - 1ull)

__device__ __forceinline__ float waveReduceSum(float v) {
#pragma unroll
  for (int off = 32; off > 0; off >>= 1) v += __shfl_xor(v, off, 64);
  return v;
}

// ---------------- init: zero the completion counters ------------------------
__global__ void init_kernel(unsigned int* __restrict__ rowcnt,
                            unsigned int* __restrict__ donecnt) {
  const int t = threadIdx.x;
  if (t < MROWS) rowcnt[t] = 0u;
  if (t == 0) donecnt[0] = 0u;
}

// ---------------- fused: stream + histogram + row-solve + final -------------
__global__ __launch_bounds__(TPB) void fused_kernel(
    const float* __restrict__ logits, const float* __restrict__ pos,
    unsigned long long* __restrict__ gh, float* __restrict__ rowout,
    unsigned int* __restrict__ rowcnt, unsigned int* __restrict__ donecnt,
    float* __restrict__ out) {
  __shared__ unsigned long long h[NBINS];
  __shared__ int winflag;
  const int blk = blockIdx.x;
  const int row = blk >> 3, chunk = blk & 7;
  const int tid = threadIdx.x, lane = tid & 63;

  h[tid] = 0ull;                          // TPB == NBINS
  __syncthreads();

  const float4* z4 = (const float4*)(logits + (size_t)row * NCOLS + (size_t)chunk * CELEMS);
  const float4* p4 = (const float4*)(pos + (size_t)row * NCOLS + (size_t)chunk * CELEMS);

  // ---- issue ALL 8 loads back-to-back (interleaved z/p), pin above uses
  float4 za[4], pa[4];
#pragma unroll
  for (int i = 0; i < 4; ++i) {
    za[i] = z4[i * TPB + tid];
    pa[i] = p4[i * TPB + tid];
  }
  __builtin_amdgcn_sched_barrier(0);

  // ---- per element: bin + pack + one 64-bit LDS atomic (deterministic)
#pragma unroll
  for (int i = 0; i < 4; ++i) {
    float zz[4] = {za[i].x, za[i].y, za[i].z, za[i].w};
    float pp[4] = {pa[i].x, pa[i].y, pa[i].z, pa[i].w};
#pragma unroll
    for (int c = 0; c < 4; ++c) {
      int b = (int)((zz[c] + ZLO) * INVW);
      b = min(max(b, 0), NBINS - 1);
      unsigned long long pk = (1ull << CNT_SHIFT) |
          (unsigned long long)(unsigned int)__float2int_rn(pp[c] * PSCALE);
      atomicAdd(&h[b], pk);
    }
  }
  __syncthreads();
  gh[(size_t)blk * NBINS + tid] = h[tid];
  __syncthreads();                        // drain gh stores (vmcnt0 before barrier)

  // ---- publish chunk; 8th arrival owns the row
  if (tid == 0) {
    unsigned int old = __hip_atomic_fetch_add(rowcnt + row, 1u,
                                              __ATOMIC_RELEASE, __HIP_MEMORY_SCOPE_AGENT);
    if (old == CHUNKS - 1) { __threadfence(); winflag = 1; } else winflag = 0;
  }
  __syncthreads();
  if (!winflag) return;

  // ---- row winner: merge 8 chunk histograms (1 bin per thread)
  {
    const size_t base = (size_t)row * CHUNKS * NBINS + tid;
    unsigned long long s = 0ull;
#pragma unroll
    for (int ch = 0; ch < CHUNKS; ++ch) s += gh[base + (size_t)ch * NBINS];
    h[tid] = s;
  }
  __syncthreads();
  if (tid >= 64) return;                  // wave 0 finishes the row

  float cnt[8], pb[8], zc[8];
  float Kh = 0.0f, Szp = 0.0f;
#pragma unroll
  for (int j = 0; j < 8; ++j) {
    const int b = lane + 64 * j;
    const unsigned long long v = h[b];
    cnt[j] = (float)(unsigned int)(v >> CNT_SHIFT);
    pb[j] = (float)(v & POS_MASK) * (1.0f / PSCALE);
    zc[j] = -ZLO + ((float)b + 0.5f) * BINW;
    Kh += pb[j];
    Szp += zc[j] * pb[j];
  }
  Kh = waveReduceSum(Kh);                 // fixed shuffle tree: deterministic
  Szp = waveReduceSum(Szp);
  const float K = fminf(fmaxf(Kh * 0.25f, 0.0f), (float)NCOLS);

  // safeguarded Newton/bisection on the merged histogram (wave-uniform)
  float Lb = -2.0f * ZLO, Ub = 2.0f * ZLO, lam = 0.0f;
  for (int it = 0; it < 40; ++it) {
    float fp = 0.0f, sp = 0.0f;
#pragma unroll
    for (int j = 0; j < 8; ++j) {
      const float p = 1.0f / (1.0f + __expf(-(zc[j] + lam)));
      fp += cnt[j] * p;
      sp += cnt[j] * p * (1.0f - p);
    }
    fp = waveReduceSum(fp);
    sp = waveReduceSum(sp);
    const float f = fp - K;
    if (fabsf(f) <= 1e-2f) break;
    if (f > 0.0f) Ub = lam; else Lb = lam;
    const float newton = lam - f / (sp + 1e-12f);
    lam = (newton > Lb && newton < Ub) ? newton : 0.5f * (Lb + Ub);
  }

  // binned BCE + dice partials
  float tl = 0.0f, ti = 0.0f, tp = 0.0f;
#pragma unroll
  for (int j = 0; j < 8; ++j) {
    const float zs = zc[j] + lam;
    const float e = __expf(-fabsf(zs));
    const float lg = __logf(1.0f + e);
    const float mz = fmaxf(zs, 0.0f);
    const float sig = (zs >= 0.0f) ? (1.0f / (1.0f + e)) : (e / (1.0f + e));
    tl += cnt[j] * (mz + lg);
    ti += pb[j] * sig;
    tp += cnt[j] * sig;
  }
  tl = waveReduceSum(tl);
  ti = waveReduceSum(ti);
  tp = waveReduceSum(tp);

  int fin = 0;
  if (lane == 0) {
    float* o = rowout + row * 4;
    o[0] = 4.0f * tl - (Szp + lam * Kh);  // block-weighted BCE row sum
    o[1] = ti;
    o[2] = tp;
    o[3] = Kh;
    const unsigned int od = __hip_atomic_fetch_add(donecnt, 1u,
                                                   __ATOMIC_RELEASE, __HIP_MEMORY_SCOPE_AGENT);
    if (od == MROWS - 1) { __threadfence(); fin = 1; }
  }
  fin = __shfl(fin, 0, 64);
  if (!fin) return;

  // ---- grid winner: combine 256 rows into the two scalars (4 rows/lane)
  float mc = 0.0f, dc = 0.0f;
#pragma unroll
  for (int k = 0; k < 4; ++k) {
    const float* o = rowout + (lane + 64 * k) * 4;
    mc += o[0] * (1.0f / (512.0f * 512.0f));
    dc += 1.0f - (2.0f * o[1] + 1.0f) / (4.0f * o[2] + o[3] + 1.0f);
  }
  mc = waveReduceSum(mc);
  dc = waveReduceSum(dc);
  if (lane == 0) {
    out[0] = mc * (1.0f / 256.0f);
    out[1] = dc * (1.0f / 256.0f);
  }
}

// -------- fallback (round-2 style, 4 KB ws) in case ws is too small ---------
#define FB_TPB 1024
#define FB_NV4 (NCOLS / 4 / FB_TPB)
__device__ __forceinline__ void fbReduce2(float a, float b, float* red,
                                          int wid, int lane, float& A, float& B) {
  a = waveReduceSum(a);
  b = waveReduceSum(b);
  __syncthreads();
  if (lane == 0) { red[wid] = a; red[16 + wid] = b; }
  __syncthreads();
  float ta = 0.0f, tb = 0.0f;
#pragma unroll
  for (int j = 0; j < 16; ++j) { ta += red[j]; tb += red[16 + j]; }
  A = ta; B = tb;
}

__global__ __launch_bounds__(FB_TPB) void fb_row_kernel(
    const float* __restrict__ logits, const float* __restrict__ pos,
    float* __restrict__ rowout) {
  __shared__ unsigned int h_cnt[2048];
  __shared__ int h_sum[2048];
  __shared__ float red[64];
  const int row = blockIdx.x;
  const int tid = threadIdx.x, wid = tid >> 6, lane = tid & 63;
  const float4* z4 = (const float4*)(logits + (size_t)row * NCOLS);
  const float4* p4 = (const float4*)(pos + (size_t)row * NCOLS);
  for (int b = tid; b < 2048; b += FB_TPB) { h_cnt[b] = 0u; h_sum[b] = 0; }
  __syncthreads();
  const float invw = 2048.0f / 40.0f;
  float s_pos = 0.0f;
#pragma unroll
  for (int i = 0; i < FB_NV4; ++i) {
    float4 zv = z4[i * FB_TPB + tid];
    float4 pv = p4[i * FB_TPB + tid];
    s_pos += (pv.x + pv.y) + (pv.z + pv.w);
    float zz[4] = {zv.x, zv.y, zv.z, zv.w};
#pragma unroll
    for (int c = 0; c < 4; ++c) {
      int b = (int)((zz[c] + 20.0f) * invw);
      b = min(max(b, 0), 2047);
      atomicAdd(&h_cnt[b], 1u);
      atomicAdd(&h_sum[b], __float2int_rn(zz[c] * 1024.0f));
    }
  }
  float K_high, dummy;
  fbReduce2(s_pos, 0.0f, red, wid, lane, K_high, dummy);
  float K = fminf(fmaxf(K_high * 0.25f, 0.0f), (float)NCOLS);
  const float c0 = (float)h_cnt[tid];
  const float c1 = (float)h_cnt[tid + FB_TPB];
  const float zb0 = (c0 > 0.0f) ? (float)h_sum[tid] / (1024.0f * c0) : 0.0f;
  const float zb1 = (c1 > 0.0f) ? (float)h_sum[tid + FB_TPB] / (1024.0f * c1) : 0.0f;
  float Lb = -40.0f, Ub = 40.0f, lam = 0.0f;
  for (int it = 0; it < 40; ++it) {
    float p0 = 1.0f / (1.0f + __expf(-(zb0 + lam)));
    float p1 = 1.0f / (1.0f + __expf(-(zb1 + lam)));
    float F, S;
    fbReduce2(c0 * p0 + c1 * p1, c0 * p0 * (1.0f - p0) + c1 * p1 * (1.0f - p1),
              red, wid, lane, F, S);
    float f = F - K;
    if (fabsf(f) <= 1e-3f) break;
    if (f > 0.0f) Ub = lam; else Lb = lam;
    float newton = lam - f / (S + 1e-12f);
    lam = (newton > Lb && newton < Ub) ? newton : 0.5f * (Lb + Ub);
  }
  float loss = 0.0f, inter = 0.0f, psum = 0.0f;
#pragma unroll
  for (int i = 0; i < FB_NV4; ++i) {
    float4 zv = z4[i * FB_TPB + tid];
    float4 pv = p4[i * FB_TPB + tid];
    float zz[4] = {zv.x, zv.y, zv.z, zv.w};
    float pp[4] = {pv.x, pv.y, pv.z, pv.w};
#pragma unroll
    for (int c = 0; c < 4; ++c) {
      float zs = zz[c] + lam;
      float q = __expf(-fabsf(zs));
      loss += 4.0f * fmaxf(zs, 0.0f) - zs * pp[c] + 4.0f * __logf(1.0f + q);
      float sig = (zs >= 0.0f) ? (1.0f / (1.0f + q)) : (q / (1.0f + q));
      inter += sig * pp[c];
      psum += sig;
    }
  }
  float TL, TI;
  fbReduce2(loss, inter, red, wid, lane, TL, TI);
  float TP, d2;
  fbReduce2(psum, 0.0f, red, wid, lane, TP, d2);
  if (tid == 0) {
    float* o = rowout + row * 4;
    o[0] = TL; o[1] = TI; o[2] = TP; o[3] = K_high;
  }
}

__global__ void final_kernel(const float* __restrict__ rowout, float* __restrict__ out) {
  const int t = threadIdx.x;               // 256 threads, 4 waves
  const float loss = rowout[t * 4 + 0];
  const float inter = rowout[t * 4 + 1];
  const float psum = rowout[t * 4 + 2];
  const float Kh = rowout[t * 4 + 3];
  float maskc = loss * (1.0f / (512.0f * 512.0f));
  float dicec = 1.0f - (2.0f * inter + 1.0f) / (4.0f * psum + Kh + 1.0f);
  maskc = waveReduceSum(maskc);
  dicec = waveReduceSum(dicec);
  __shared__ float red[8];
  const int wid = t >> 6, lane = t & 63;
  if (lane == 0) { red[wid] = maskc; red[4 + wid] = dicec; }
  __syncthreads();
  if (t == 0) {
    float a = 0.0f, b = 0.0f;
    for (int j = 0; j < 4; ++j) { a += red[j]; b += red[4 + j]; }
    out[0] = a / 256.0f;
    out[1] = b / 256.0f;
  }
}

extern "C" void kernel_launch(void* const* d_in, const int* in_sizes, int n_in,
                              void* d_out, int out_size, void* d_ws, size_t ws_size,
                              hipStream_t stream) {
  const float* logits = (const float*)d_in[0];
  const float* pos = (const float*)d_in[1];
  char* ws = (char*)d_ws;

  const size_t nblk = (size_t)MROWS * CHUNKS;               // 2048
  const size_t off_gh = 0;
  const size_t off_rowout = off_gh + nblk * NBINS * sizeof(unsigned long long);
  const size_t off_rowcnt = off_rowout + (size_t)MROWS * 4 * sizeof(float);
  const size_t off_donecnt = off_rowcnt + (size_t)MROWS * sizeof(unsigned int);
  const size_t needed = off_donecnt + sizeof(unsigned int);

  if (ws_size >= needed) {
    unsigned long long* gh = (unsigned long long*)(ws + off_gh);
    float* rowout = (float*)(ws + off_rowout);
    unsigned int* rowcnt = (unsigned int*)(ws + off_rowcnt);
    unsigned int* donecnt = (unsigned int*)(ws + off_donecnt);
    init_kernel<<<1, 256, 0, stream>>>(rowcnt, donecnt);
    fused_kernel<<<(int)nblk, TPB, 0, stream>>>(logits, pos, gh, rowout,
                                                rowcnt, donecnt, (float*)d_out);
  } else {
    float* rowout = (float*)d_ws;          // 4 KB fallback path
    fb_row_kernel<<<MROWS, FB_TPB, 0, stream>>>(logits, pos, rowout);
    final_kernel<<<1, 256, 0, stream>>>(rowout, (float*)d_out);
  }
}

// Round 6
// 34.127 us; speedup vs baseline: 4.8806x; 4.8806x over previous
//
#include <hip/hip_runtime.h>
#include <math.h>

#define NCOLS 65536
#define MROWS 256
#define NBINS 512
#define CHUNKS 32
#define CELEMS (NCOLS / CHUNKS)          // 2048 elements per chunk
#define K1_TPB 256
#define K1_IT (CELEMS / 4 / K1_TPB)      // 2 float4 iterations per thread
#define ZLO 20.0f
#define INVW ((float)NBINS / (2.0f * ZLO))   // 12.8 bins per unit
#define BINW (2.0f * ZLO / (float)NBINS)     // 0.078125
#define PSCALE 64.0f
#define CNT_SHIFT 20
#define POS_MASK 0xFFFFFu

__device__ __forceinline__ float waveReduceSum(float v) {
#pragma unroll
  for (int off = 32; off > 0; off >>= 1) v += __shfl_xor(v, off, 64);
  return v;
}

// ------------- K1: stream once; per-chunk packed 32-bit histogram -----------
__global__ __launch_bounds__(K1_TPB) void hist_kernel(
    const float* __restrict__ logits, const float* __restrict__ pos,
    unsigned int* __restrict__ gh) {
  __shared__ unsigned int h[NBINS];
  const int blk = blockIdx.x;
  const int row = blk / CHUNKS, chunk = blk % CHUNKS;
  const int tid = threadIdx.x;

  h[tid] = 0u;
  h[tid + K1_TPB] = 0u;
  __syncthreads();

  const float4* z4 = (const float4*)(logits + (size_t)row * NCOLS + (size_t)chunk * CELEMS);
  const float4* p4 = (const float4*)(pos + (size_t)row * NCOLS + (size_t)chunk * CELEMS);

  // issue all 4 loads up-front; 16 VGPRs of data, no clamp => stays in regs
  float4 za[K1_IT], pa[K1_IT];
#pragma unroll
  for (int i = 0; i < K1_IT; ++i) {
    za[i] = z4[i * K1_TPB + tid];
    pa[i] = p4[i * K1_TPB + tid];
  }
  __builtin_amdgcn_sched_barrier(0);

#pragma unroll
  for (int i = 0; i < K1_IT; ++i) {
    float zz[4] = {za[i].x, za[i].y, za[i].z, za[i].w};
    float pp[4] = {pa[i].x, pa[i].y, pa[i].z, pa[i].w};
#pragma unroll
    for (int c = 0; c < 4; ++c) {
      int b = (int)((zz[c] + ZLO) * INVW);
      b = min(max(b, 0), NBINS - 1);
      unsigned int pk = (1u << CNT_SHIFT) |
                        (unsigned int)__float2int_rn(pp[c] * PSCALE);
      atomicAdd(&h[b], pk);               // integer: deterministic
    }
  }
  __syncthreads();
  const size_t base = (size_t)blk * NBINS;
  gh[base + tid] = h[tid];
  gh[base + tid + K1_TPB] = h[tid + K1_TPB];
}

// ------------- K2: merge + wave-0 Newton + binned eval ----------------------
#define K2_TPB 256

__global__ __launch_bounds__(K2_TPB) void solve_kernel(
    const unsigned int* __restrict__ gh, float* __restrict__ rowout) {
  __shared__ float cs[NBINS], ps[NBINS];
  const int row = blockIdx.x;
  const int tid = threadIdx.x;

  // merge 32 chunk histograms, unpacked 32-bit sums (fixed order: deterministic)
#pragma unroll
  for (int j = 0; j < NBINS / K2_TPB; ++j) {
    const int b = tid + j * K2_TPB;
    unsigned int c = 0u, q = 0u;
    const size_t base = (size_t)row * CHUNKS * NBINS + b;
#pragma unroll
    for (int ch = 0; ch < CHUNKS; ++ch) {
      const unsigned int v = gh[base + (size_t)ch * NBINS];
      c += v >> CNT_SHIFT;                // <= 65536
      q += v & POS_MASK;                  // <= 32 * 2^19 < 2^32
    }
    cs[b] = (float)c;
    ps[b] = (float)q * (1.0f / PSCALE);
  }
  __syncthreads();
  if (tid >= 64) return;                  // wave 0 finishes the row

  const int lane = tid;
  float cnt[8], pb[8], zc[8];
  float Kh = 0.0f, Szp = 0.0f;
#pragma unroll
  for (int j = 0; j < 8; ++j) {
    const int b = lane + 64 * j;
    cnt[j] = cs[b];
    pb[j] = ps[b];
    zc[j] = -ZLO + ((float)b + 0.5f) * BINW;
    Kh += pb[j];
    Szp += zc[j] * pb[j];
  }
  Kh = waveReduceSum(Kh);                 // fixed shuffle tree: deterministic
  Szp = waveReduceSum(Szp);
  const float K = fminf(fmaxf(Kh * 0.25f, 0.0f), (float)NCOLS);

  // safeguarded Newton/bisection on the merged histogram (wave-uniform)
  float Lb = -2.0f * ZLO, Ub = 2.0f * ZLO, lam = 0.0f;
  for (int it = 0; it < 40; ++it) {
    float fp = 0.0f, sp = 0.0f;
#pragma unroll
    for (int j = 0; j < 8; ++j) {
      const float p = 1.0f / (1.0f + __expf(-(zc[j] + lam)));
      fp += cnt[j] * p;
      sp += cnt[j] * p * (1.0f - p);
    }
    fp = waveReduceSum(fp);
    sp = waveReduceSum(sp);
    const float f = fp - K;
    if (fabsf(f) <= 1e-2f) break;
    if (f > 0.0f) Ub = lam; else Lb = lam;
    const float newton = lam - f / (sp + 1e-12f);
    lam = (newton > Lb && newton < Ub) ? newton : 0.5f * (Lb + Ub);
  }

  // binned BCE + dice partials
  float tl = 0.0f, ti = 0.0f, tp = 0.0f;
#pragma unroll
  for (int j = 0; j < 8; ++j) {
    const float zs = zc[j] + lam;
    const float e = __expf(-fabsf(zs));
    const float lg = __logf(1.0f + e);
    const float mz = fmaxf(zs, 0.0f);
    const float sig = (zs >= 0.0f) ? (1.0f / (1.0f + e)) : (e / (1.0f + e));
    tl += cnt[j] * (mz + lg);
    ti += pb[j] * sig;
    tp += cnt[j] * sig;
  }
  tl = waveReduceSum(tl);
  ti = waveReduceSum(ti);
  tp = waveReduceSum(tp);
  if (lane == 0) {
    float* o = rowout + row * 4;
    o[0] = 4.0f * tl - (Szp + lam * Kh);  // block-weighted BCE row sum
    o[1] = ti;
    o[2] = tp;
    o[3] = Kh;
  }
}

// ---------------- K3: combine 256 rows into the two scalars -----------------
__global__ void final_kernel(const float* __restrict__ rowout, float* __restrict__ out) {
  const int t = threadIdx.x;               // 256 threads, 4 waves
  const float loss = rowout[t * 4 + 0];
  const float inter = rowout[t * 4 + 1];
  const float psum = rowout[t * 4 + 2];
  const float Kh = rowout[t * 4 + 3];
  float maskc = loss * (1.0f / (512.0f * 512.0f));
  float dicec = 1.0f - (2.0f * inter + 1.0f) / (4.0f * psum + Kh + 1.0f);
  maskc = waveReduceSum(maskc);
  dicec = waveReduceSum(dicec);
  __shared__ float red[8];
  const int wid = t >> 6, lane = t & 63;
  if (lane == 0) { red[wid] = maskc; red[4 + wid] = dicec; }
  __syncthreads();
  if (t == 0) {
    float a = 0.0f, b = 0.0f;
    for (int j = 0; j < 4; ++j) { a += red[j]; b += red[4 + j]; }
    out[0] = a / 256.0f;
    out[1] = b / 256.0f;
  }
}

// -------- fallback (round-2 style, 4 KB ws) in case ws is too small ---------
#define FB_TPB 1024
#define FB_NV4 (NCOLS / 4 / FB_TPB)
__device__ __forceinline__ void fbReduce2(float a, float b, float* red,
                                          int wid, int lane, float& A, float& B) {
  a = waveReduceSum(a);
  b = waveReduceSum(b);
  __syncthreads();
  if (lane == 0) { red[wid] = a; red[16 + wid] = b; }
  __syncthreads();
  float ta = 0.0f, tb = 0.0f;
#pragma unroll
  for (int j = 0; j < 16; ++j) { ta += red[j]; tb += red[16 + j]; }
  A = ta; B = tb;
}

__global__ __launch_bounds__(FB_TPB) void fb_row_kernel(
    const float* __restrict__ logits, const float* __restrict__ pos,
    float* __restrict__ rowout) {
  __shared__ unsigned int h_cnt[2048];
  __shared__ int h_sum[2048];
  __shared__ float red[64];
  const int row = blockIdx.x;
  const int tid = threadIdx.x, wid = tid >> 6, lane = tid & 63;
  const float4* z4 = (const float4*)(logits + (size_t)row * NCOLS);
  const float4* p4 = (const float4*)(pos + (size_t)row * NCOLS);
  for (int b = tid; b < 2048; b += FB_TPB) { h_cnt[b] = 0u; h_sum[b] = 0; }
  __syncthreads();
  const float invw = 2048.0f / 40.0f;
  float s_pos = 0.0f;
#pragma unroll
  for (int i = 0; i < FB_NV4; ++i) {
    float4 zv = z4[i * FB_TPB + tid];
    float4 pv = p4[i * FB_TPB + tid];
    s_pos += (pv.x + pv.y) + (pv.z + pv.w);
    float zz[4] = {zv.x, zv.y, zv.z, zv.w};
#pragma unroll
    for (int c = 0; c < 4; ++c) {
      int b = (int)((zz[c] + 20.0f) * invw);
      b = min(max(b, 0), 2047);
      atomicAdd(&h_cnt[b], 1u);
      atomicAdd(&h_sum[b], __float2int_rn(zz[c] * 1024.0f));
    }
  }
  float K_high, dummy;
  fbReduce2(s_pos, 0.0f, red, wid, lane, K_high, dummy);
  float K = fminf(fmaxf(K_high * 0.25f, 0.0f), (float)NCOLS);
  const float c0 = (float)h_cnt[tid];
  const float c1 = (float)h_cnt[tid + FB_TPB];
  const float zb0 = (c0 > 0.0f) ? (float)h_sum[tid] / (1024.0f * c0) : 0.0f;
  const float zb1 = (c1 > 0.0f) ? (float)h_sum[tid + FB_TPB] / (1024.0f * c1) : 0.0f;
  float Lb = -40.0f, Ub = 40.0f, lam = 0.0f;
  for (int it = 0; it < 40; ++it) {
    float p0 = 1.0f / (1.0f + __expf(-(zb0 + lam)));
    float p1 = 1.0f / (1.0f + __expf(-(zb1 + lam)));
    float F, S;
    fbReduce2(c0 * p0 + c1 * p1, c0 * p0 * (1.0f - p0) + c1 * p1 * (1.0f - p1),
              red, wid, lane, F, S);
    float f = F - K;
    if (fabsf(f) <= 1e-3f) break;
    if (f > 0.0f) Ub = lam; else Lb = lam;
    float newton = lam - f / (S + 1e-12f);
    lam = (newton > Lb && newton < Ub) ? newton : 0.5f * (Lb + Ub);
  }
  float loss = 0.0f, inter = 0.0f, psum = 0.0f;
#pragma unroll
  for (int i = 0; i < FB_NV4; ++i) {
    float4 zv = z4[i * FB_TPB + tid];
    float4 pv = p4[i * FB_TPB + tid];
    float zz[4] = {zv.x, zv.y, zv.z, zv.w};
    float pp[4] = {pv.x, pv.y, pv.z, pv.w};
#pragma unroll
    for (int c = 0; c < 4; ++c) {
      float zs = zz[c] + lam;
      float q = __expf(-fabsf(zs));
      loss += 4.0f * fmaxf(zs, 0.0f) - zs * pp[c] + 4.0f * __logf(1.0f + q);
      float sig = (zs >= 0.0f) ? (1.0f / (1.0f + q)) : (q / (1.0f + q));
      inter += sig * pp[c];
      psum += sig;
    }
  }
  float TL, TI;
  fbReduce2(loss, inter, red, wid, lane, TL, TI);
  float TP, d2;
  fbReduce2(psum, 0.0f, red, wid, lane, TP, d2);
  if (tid == 0) {
    float* o = rowout + row * 4;
    o[0] = TL; o[1] = TI; o[2] = TP; o[3] = K_high;
  }
}

extern "C" void kernel_launch(void* const* d_in, const int* in_sizes, int n_in,
                              void* d_out, int out_size, void* d_ws, size_t ws_size,
                              hipStream_t stream) {
  const float* logits = (const float*)d_in[0];
  const float* pos = (const float*)d_in[1];
  char* ws = (char*)d_ws;

  const size_t nblk = (size_t)MROWS * CHUNKS;               // 8192
  const size_t off_gh = 0;
  const size_t off_rowout = off_gh + nblk * NBINS * sizeof(unsigned int);
  const size_t needed = off_rowout + (size_t)MROWS * 4 * sizeof(float);

  if (ws_size >= needed) {
    unsigned int* gh = (unsigned int*)(ws + off_gh);
    float* rowout = (float*)(ws + off_rowout);
    hist_kernel<<<(int)nblk, K1_TPB, 0, stream>>>(logits, pos, gh);
    solve_kernel<<<MROWS, K2_TPB, 0, stream>>>(gh, rowout);
    final_kernel<<<1, 256, 0, stream>>>(rowout, (float*)d_out);
  } else {
    float* rowout = (float*)d_ws;          // 4 KB fallback path
    fb_row_kernel<<<MROWS, FB_TPB, 0, stream>>>(logits, pos, rowout);
    final_kernel<<<1, 256, 0, stream>>>(rowout, (float*)d_out);
  }
}

// Round 7
// 32.780 us; speedup vs baseline: 5.0811x; 1.0411x over previous
//
#include <hip/hip_runtime.h>
#include <math.h>

#define NCOLS 65536
#define MROWS 256
#define NBINS 512
#define CHUNKS 16
#define CELEMS (NCOLS / CHUNKS)          // 4096 elements per chunk
#define K1_TPB 256
#define ZLO 20.0f
#define INVW ((float)NBINS / (2.0f * ZLO))   // 12.8 bins per unit
#define BINW (2.0f * ZLO / (float)NBINS)     // 0.078125
#define PSCALE 32.0f
#define CNT_SHIFT 20
#define POS_MASK ((1u << CNT_SHIFT) - 1u)

// async global->LDS DMA, 16B per lane; LDS dest = wave-uniform base + lane*16
#define GL16(gsrc, ldst) __builtin_amdgcn_global_load_lds(                    \
    (const __attribute__((address_space(1))) void*)(gsrc),                    \
    (__attribute__((address_space(3))) void*)(ldst), 16, 0, 0)

__device__ __forceinline__ float waveReduceSum(float v) {
#pragma unroll
  for (int off = 32; off > 0; off >>= 1) v += __shfl_xor(v, off, 64);
  return v;
}

// ------------- K1: DMA-stage chunk to LDS; packed 32-bit histogram ----------
__global__ __launch_bounds__(K1_TPB) void hist_kernel(
    const float* __restrict__ logits, const float* __restrict__ pos,
    unsigned int* __restrict__ gh) {
  __shared__ __align__(16) float zb[CELEMS];
  __shared__ __align__(16) float pb[CELEMS];
  __shared__ unsigned int h[NBINS];
  const int blk = blockIdx.x;
  const int row = blk / CHUNKS, chunk = blk % CHUNKS;
  const int tid = threadIdx.x;
  const int wv = tid >> 6, ln = tid & 63;

  h[tid] = 0u;
  h[tid + K1_TPB] = 0u;

  const float* zsrc = logits + (size_t)row * NCOLS + (size_t)chunk * CELEMS;
  const float* psrc = pos + (size_t)row * NCOLS + (size_t)chunk * CELEMS;

  // each wave DMA-stages its own 1024-float quarter of zb and pb:
  // 8 global_load_lds_dwordx4 issued back-to-back -> 8 KB in flight per wave,
  // zero data VGPRs (this is the concurrency the allocator kept denying us).
#pragma unroll
  for (int s = 0; s < 4; ++s) {
    const int off = wv * 1024 + s * 256;      // float index, wave-uniform
    GL16(zsrc + off + ln * 4, &zb[off]);
    GL16(psrc + off + ln * 4, &pb[off]);
  }
  asm volatile("s_waitcnt vmcnt(0)" ::: "memory");
  __syncthreads();                            // h zeroed + all staging visible

  // consume own wave's granules: lane l reads its 16B -> conflict-free b128
#pragma unroll
  for (int s = 0; s < 4; ++s) {
    const int off = wv * 1024 + s * 256 + ln * 4;
    const float4 zv = *(const float4*)&zb[off];
    const float4 pv = *(const float4*)&pb[off];
    float zz[4] = {zv.x, zv.y, zv.z, zv.w};
    float pp[4] = {pv.x, pv.y, pv.z, pv.w};
#pragma unroll
    for (int c = 0; c < 4; ++c) {
      int b = (int)((zz[c] + ZLO) * INVW);
      b = min(max(b, 0), NBINS - 1);
      // pack: cnt in bits [20,32) (<=4096 fits), pos*32 in bits [0,20)
      // worst case possum = 4096 * round(3.9999*32)=128 -> 524288 < 2^20  OK
      unsigned int pk = (1u << CNT_SHIFT) |
                        (unsigned int)__float2int_rn(pp[c] * PSCALE);
      atomicAdd(&h[b], pk);                   // integer: deterministic
    }
  }
  __syncthreads();
  const size_t base = (size_t)blk * NBINS;
  gh[base + tid] = h[tid];
  gh[base + tid + K1_TPB] = h[tid + K1_TPB];
}

// ------------- K2: merge + wave-0 Newton + binned eval ----------------------
#define K2_TPB 256

__global__ __launch_bounds__(K2_TPB) void solve_kernel(
    const unsigned int* __restrict__ gh, float* __restrict__ rowout) {
  __shared__ float cs[NBINS], ps[NBINS];
  const int row = blockIdx.x;
  const int tid = threadIdx.x;

  // merge 16 chunk histograms, unpacked 32-bit sums (fixed order: deterministic)
#pragma unroll
  for (int j = 0; j < NBINS / K2_TPB; ++j) {
    const int b = tid + j * K2_TPB;
    unsigned int c = 0u, q = 0u;
    const size_t base = (size_t)row * CHUNKS * NBINS + b;
#pragma unroll
    for (int ch = 0; ch < CHUNKS; ++ch) {
      const unsigned int v = gh[base + (size_t)ch * NBINS];
      c += v >> CNT_SHIFT;                // <= 65536
      q += v & POS_MASK;                  // <= 16 * 2^20 < 2^32
    }
    cs[b] = (float)c;
    ps[b] = (float)q * (1.0f / PSCALE);
  }
  __syncthreads();
  if (tid >= 64) return;                  // wave 0 finishes the row

  const int lane = tid;
  float cnt[8], pb[8], zc[8];
  float Kh = 0.0f, Szp = 0.0f;
#pragma unroll
  for (int j = 0; j < 8; ++j) {
    const int b = lane + 64 * j;
    cnt[j] = cs[b];
    pb[j] = ps[b];
    zc[j] = -ZLO + ((float)b + 0.5f) * BINW;
    Kh += pb[j];
    Szp += zc[j] * pb[j];
  }
  Kh = waveReduceSum(Kh);                 // fixed shuffle tree: deterministic
  Szp = waveReduceSum(Szp);
  const float K = fminf(fmaxf(Kh * 0.25f, 0.0f), (float)NCOLS);

  // safeguarded Newton/bisection on the merged histogram (wave-uniform)
  float Lb = -2.0f * ZLO, Ub = 2.0f * ZLO, lam = 0.0f;
  for (int it = 0; it < 40; ++it) {
    float fp = 0.0f, sp = 0.0f;
#pragma unroll
    for (int j = 0; j < 8; ++j) {
      const float p = 1.0f / (1.0f + __expf(-(zc[j] + lam)));
      fp += cnt[j] * p;
      sp += cnt[j] * p * (1.0f - p);
    }
    fp = waveReduceSum(fp);
    sp = waveReduceSum(sp);
    const float f = fp - K;
    if (fabsf(f) <= 1e-2f) break;
    if (f > 0.0f) Ub = lam; else Lb = lam;
    const float newton = lam - f / (sp + 1e-12f);
    lam = (newton > Lb && newton < Ub) ? newton : 0.5f * (Lb + Ub);
  }

  // binned BCE + dice partials
  float tl = 0.0f, ti = 0.0f, tp = 0.0f;
#pragma unroll
  for (int j = 0; j < 8; ++j) {
    const float zs = zc[j] + lam;
    const float e = __expf(-fabsf(zs));
    const float lg = __logf(1.0f + e);
    const float mz = fmaxf(zs, 0.0f);
    const float sig = (zs >= 0.0f) ? (1.0f / (1.0f + e)) : (e / (1.0f + e));
    tl += cnt[j] * (mz + lg);
    ti += pb[j] * sig;
    tp += cnt[j] * sig;
  }
  tl = waveReduceSum(tl);
  ti = waveReduceSum(ti);
  tp = waveReduceSum(tp);
  if (lane == 0) {
    float* o = rowout + row * 4;
    o[0] = 4.0f * tl - (Szp + lam * Kh);  // block-weighted BCE row sum
    o[1] = ti;
    o[2] = tp;
    o[3] = Kh;
  }
}

// ---------------- K3: combine 256 rows into the two scalars -----------------
__global__ void final_kernel(const float* __restrict__ rowout, float* __restrict__ out) {
  const int t = threadIdx.x;               // 256 threads, 4 waves
  const float loss = rowout[t * 4 + 0];
  const float inter = rowout[t * 4 + 1];
  const float psum = rowout[t * 4 + 2];
  const float Kh = rowout[t * 4 + 3];
  float maskc = loss * (1.0f / (512.0f * 512.0f));
  float dicec = 1.0f - (2.0f * inter + 1.0f) / (4.0f * psum + Kh + 1.0f);
  maskc = waveReduceSum(maskc);
  dicec = waveReduceSum(dicec);
  __shared__ float red[8];
  const int wid = t >> 6, lane = t & 63;
  if (lane == 0) { red[wid] = maskc; red[4 + wid] = dicec; }
  __syncthreads();
  if (t == 0) {
    float a = 0.0f, b = 0.0f;
    for (int j = 0; j < 4; ++j) { a += red[j]; b += red[4 + j]; }
    out[0] = a / 256.0f;
    out[1] = b / 256.0f;
  }
}

// -------- fallback (round-2 style, 4 KB ws) in case ws is too small ---------
#define FB_TPB 1024
#define FB_NV4 (NCOLS / 4 / FB_TPB)
__device__ __forceinline__ void fbReduce2(float a, float b, float* red,
                                          int wid, int lane, float& A, float& B) {
  a = waveReduceSum(a);
  b = waveReduceSum(b);
  __syncthreads();
  if (lane == 0) { red[wid] = a; red[16 + wid] = b; }
  __syncthreads();
  float ta = 0.0f, tb = 0.0f;
#pragma unroll
  for (int j = 0; j < 16; ++j) { ta += red[j]; tb += red[16 + j]; }
  A = ta; B = tb;
}

__global__ __launch_bounds__(FB_TPB) void fb_row_kernel(
    const float* __restrict__ logits, const float* __restrict__ pos,
    float* __restrict__ rowout) {
  __shared__ unsigned int h_cnt[2048];
  __shared__ int h_sum[2048];
  __shared__ float red[64];
  const int row = blockIdx.x;
  const int tid = threadIdx.x, wid = tid >> 6, lane = tid & 63;
  const float4* z4 = (const float4*)(logits + (size_t)row * NCOLS);
  const float4* p4 = (const float4*)(pos + (size_t)row * NCOLS);
  for (int b = tid; b < 2048; b += FB_TPB) { h_cnt[b] = 0u; h_sum[b] = 0; }
  __syncthreads();
  const float invw = 2048.0f / 40.0f;
  float s_pos = 0.0f;
#pragma unroll
  for (int i = 0; i < FB_NV4; ++i) {
    float4 zv = z4[i * FB_TPB + tid];
    float4 pv = p4[i * FB_TPB + tid];
    s_pos += (pv.x + pv.y) + (pv.z + pv.w);
    float zz[4] = {zv.x, zv.y, zv.z, zv.w};
#pragma unroll
    for (int c = 0; c < 4; ++c) {
      int b = (int)((zz[c] + 20.0f) * invw);
      b = min(max(b, 0), 2047);
      atomicAdd(&h_cnt[b], 1u);
      atomicAdd(&h_sum[b], __float2int_rn(zz[c] * 1024.0f));
    }
  }
  float K_high, dummy;
  fbReduce2(s_pos, 0.0f, red, wid, lane, K_high, dummy);
  float K = fminf(fmaxf(K_high * 0.25f, 0.0f), (float)NCOLS);
  const float c0 = (float)h_cnt[tid];
  const float c1 = (float)h_cnt[tid + FB_TPB];
  const float zb0 = (c0 > 0.0f) ? (float)h_sum[tid] / (1024.0f * c0) : 0.0f;
  const float zb1 = (c1 > 0.0f) ? (float)h_sum[tid + FB_TPB] / (1024.0f * c1) : 0.0f;
  float Lb = -40.0f, Ub = 40.0f, lam = 0.0f;
  for (int it = 0; it < 40; ++it) {
    float p0 = 1.0f / (1.0f + __expf(-(zb0 + lam)));
    float p1 = 1.0f / (1.0f + __expf(-(zb1 + lam)));
    float F, S;
    fbReduce2(c0 * p0 + c1 * p1, c0 * p0 * (1.0f - p0) + c1 * p1 * (1.0f - p1),
              red, wid, lane, F, S);
    float f = F - K;
    if (fabsf(f) <= 1e-3f) break;
    if (f > 0.0f) Ub = lam; else Lb = lam;
    float newton = lam - f / (S + 1e-12f);
    lam = (newton > Lb && newton < Ub) ? newton : 0.5f * (Lb + Ub);
  }
  float loss = 0.0f, inter = 0.0f, psum = 0.0f;
#pragma unroll
  for (int i = 0; i < FB_NV4; ++i) {
    float4 zv = z4[i * FB_TPB + tid];
    float4 pv = p4[i * FB_TPB + tid];
    float zz[4] = {zv.x, zv.y, zv.z, zv.w};
    float pp[4] = {pv.x, pv.y, pv.z, pv.w};
#pragma unroll
    for (int c = 0; c < 4; ++c) {
      float zs = zz[c] + lam;
      float q = __expf(-fabsf(zs));
      loss += 4.0f * fmaxf(zs, 0.0f) - zs * pp[c] + 4.0f * __logf(1.0f + q);
      float sig = (zs >= 0.0f) ? (1.0f / (1.0f + q)) : (q / (1.0f + q));
      inter += sig * pp[c];
      psum += sig;
    }
  }
  float TL, TI;
  fbReduce2(loss, inter, red, wid, lane, TL, TI);
  float TP, d2;
  fbReduce2(psum, 0.0f, red, wid, lane, TP, d2);
  if (tid == 0) {
    float* o = rowout + row * 4;
    o[0] = TL; o[1] = TI; o[2] = TP; o[3] = K_high;
  }
}

extern "C" void kernel_launch(void* const* d_in, const int* in_sizes, int n_in,
                              void* d_out, int out_size, void* d_ws, size_t ws_size,
                              hipStream_t stream) {
  const float* logits = (const float*)d_in[0];
  const float* pos = (const float*)d_in[1];
  char* ws = (char*)d_ws;

  const size_t nblk = (size_t)MROWS * CHUNKS;               // 4096
  const size_t off_gh = 0;
  const size_t off_rowout = off_gh + nblk * NBINS * sizeof(unsigned int);
  const size_t needed = off_rowout + (size_t)MROWS * 4 * sizeof(float);

  if (ws_size >= needed) {
    unsigned int* gh = (unsigned int*)(ws + off_gh);
    float* rowout = (float*)(ws + off_rowout);
    hist_kernel<<<(int)nblk, K1_TPB, 0, stream>>>(logits, pos, gh);
    solve_kernel<<<MROWS, K2_TPB, 0, stream>>>(gh, rowout);
    final_kernel<<<1, 256, 0, stream>>>(rowout, (float*)d_out);
  } else {
    float* rowout = (float*)d_ws;          // 4 KB fallback path
    fb_row_kernel<<<MROWS, FB_TPB, 0, stream>>>(logits, pos, rowout);
    final_kernel<<<1, 256, 0, stream>>>(rowout, (float*)d_out);
  }
}

// Round 8
// 32.212 us; speedup vs baseline: 5.1707x; 1.0176x over previous
//
#include <hip/hip_runtime.h>
#include <math.h>

#define NCOLS 65536
#define MROWS 256
#define NBINS 512
#define SUBE 2048                       // elements per sub-chunk (8 KB)
#define NSUB 8                          // sub-chunks per block
#define BLKE (SUBE * NSUB)              // 16384 elements per block
#define BPR (NCOLS / BLKE)              // 4 blocks per row
#define K1_TPB 256
#define ZLO 20.0f
#define INVW ((float)NBINS / (2.0f * ZLO))   // 12.8 bins per unit
#define BINW (2.0f * ZLO / (float)NBINS)     // 0.078125
#define PSCALE 8.0f
#define CNT_SHIFT 19
#define POS_MASK ((1u << CNT_SHIFT) - 1u)

// async global->LDS DMA, 16B/lane; LDS dest = wave-uniform base + lane*16
#define GL16(gsrc, ldst) __builtin_amdgcn_global_load_lds(                    \
    (const __attribute__((address_space(1))) void*)(gsrc),                    \
    (__attribute__((address_space(3))) void*)(ldst), 16, 0, 0)

__device__ __forceinline__ float waveReduceSum(float v) {
#pragma unroll
  for (int off = 32; off > 0; off >>= 1) v += __shfl_xor(v, off, 64);
  return v;
}

// ---- K1: per-wave double-buffered DMA pipeline + packed 32-bit histogram ---
__global__ __launch_bounds__(K1_TPB) void hist_kernel(
    const float* __restrict__ logits, const float* __restrict__ pos,
    unsigned int* __restrict__ gh) {
  __shared__ __align__(16) float zb[2][SUBE];
  __shared__ __align__(16) float pb[2][SUBE];
  __shared__ unsigned int h[NBINS];
  const int blk = blockIdx.x;
  const int row = blk / BPR, seg = blk % BPR;
  const int tid = threadIdx.x;
  const int wv = tid >> 6, ln = tid & 63;
  const int wq = wv * 512;              // wave-private quarter (floats)

  h[tid] = 0u;
  h[tid + K1_TPB] = 0u;

  const float* zs = logits + (size_t)row * NCOLS + (size_t)seg * BLKE;
  const float* ps = pos + (size_t)row * NCOLS + (size_t)seg * BLKE;

// stage sub-chunk c into parity buffer par: 4 GL16, wave-private region
#define STAGE(par, c) do {                                                    \
    const float* zsrc_ = zs + (c) * SUBE + wq;                                \
    const float* psrc_ = ps + (c) * SUBE + wq;                                \
    GL16(zsrc_ + ln * 4, &zb[par][wq]);                                       \
    GL16(zsrc_ + 256 + ln * 4, &zb[par][wq + 256]);                           \
    GL16(psrc_ + ln * 4, &pb[par][wq]);                                       \
    GL16(psrc_ + 256 + ln * 4, &pb[par][wq + 256]);                           \
  } while (0)

// histogram own wave's quarter of parity buffer: 8 elements per lane
#define PROC(par) do {                                                        \
    _Pragma("unroll")                                                         \
    for (int s2 = 0; s2 < 2; ++s2) {                                          \
      const float4 zv = *(const float4*)&zb[par][wq + s2 * 256 + ln * 4];     \
      const float4 pv = *(const float4*)&pb[par][wq + s2 * 256 + ln * 4];     \
      float zz[4] = {zv.x, zv.y, zv.z, zv.w};                                 \
      float pp[4] = {pv.x, pv.y, pv.z, pv.w};                                 \
      _Pragma("unroll")                                                       \
      for (int c4 = 0; c4 < 4; ++c4) {                                        \
        int b = (int)((zz[c4] + ZLO) * INVW);                                 \
        b = min(max(b, 0), NBINS - 1);                                        \
        unsigned int pk = (1u << CNT_SHIFT) |                                 \
                          (unsigned int)__float2int_rn(pp[c4] * PSCALE);      \
        atomicAdd(&h[b], pk);                                                 \
      }                                                                       \
    }                                                                         \
  } while (0)

  STAGE(0, 0);
  __syncthreads();                      // h zeroed before first atomic

  // per-wave pipeline: no barriers; counted vmcnt keeps next DMA in flight
  for (int c = 0; c < NSUB; ++c) {
    if (c + 1 < NSUB) {
      STAGE((c + 1) & 1, c + 1);
      asm volatile("s_waitcnt vmcnt(4)" ::: "memory");   // sub-chunk c ready
    } else {
      asm volatile("s_waitcnt vmcnt(0)" ::: "memory");
    }
    __builtin_amdgcn_sched_barrier(0);
    PROC(c & 1);
  }
  __syncthreads();
  const size_t base = (size_t)blk * NBINS;
  gh[base + tid] = h[tid];
  gh[base + tid + K1_TPB] = h[tid + K1_TPB];
#undef STAGE
#undef PROC
}

// ------------- K2: merge + wave-0 Newton + binned eval ----------------------
#define K2_TPB 256

__global__ __launch_bounds__(K2_TPB) void solve_kernel(
    const unsigned int* __restrict__ gh, float* __restrict__ rowout) {
  __shared__ float cs[NBINS], ps[NBINS];
  const int row = blockIdx.x;
  const int tid = threadIdx.x;

  // merge 4 block histograms, unpacked 32-bit sums (fixed order: deterministic)
#pragma unroll
  for (int j = 0; j < NBINS / K2_TPB; ++j) {
    const int b = tid + j * K2_TPB;
    unsigned int c = 0u, q = 0u;
    const size_t base = (size_t)row * BPR * NBINS + b;
#pragma unroll
    for (int ch = 0; ch < BPR; ++ch) {
      const unsigned int v = gh[base + (size_t)ch * NBINS];
      c += v >> CNT_SHIFT;
      q += v & POS_MASK;
    }
    cs[b] = (float)c;
    ps[b] = (float)q * (1.0f / PSCALE);
  }
  __syncthreads();
  if (tid >= 64) return;                  // wave 0 finishes the row

  const int lane = tid;
  float cnt[8], pb[8], zc[8];
  float Kh = 0.0f, Szp = 0.0f;
#pragma unroll
  for (int j = 0; j < 8; ++j) {
    const int b = lane + 64 * j;
    cnt[j] = cs[b];
    pb[j] = ps[b];
    zc[j] = -ZLO + ((float)b + 0.5f) * BINW;
    Kh += pb[j];
    Szp += zc[j] * pb[j];
  }
  Kh = waveReduceSum(Kh);                 // fixed shuffle tree: deterministic
  Szp = waveReduceSum(Szp);
  const float K = fminf(fmaxf(Kh * 0.25f, 0.0f), (float)NCOLS);

  // safeguarded Newton/bisection on the merged histogram (wave-uniform)
  float Lb = -2.0f * ZLO, Ub = 2.0f * ZLO, lam = 0.0f;
  for (int it = 0; it < 40; ++it) {
    float fp = 0.0f, sp = 0.0f;
#pragma unroll
    for (int j = 0; j < 8; ++j) {
      const float p = 1.0f / (1.0f + __expf(-(zc[j] + lam)));
      fp += cnt[j] * p;
      sp += cnt[j] * p * (1.0f - p);
    }
    fp = waveReduceSum(fp);
    sp = waveReduceSum(sp);
    const float f = fp - K;
    if (fabsf(f) <= 1e-2f) break;
    if (f > 0.0f) Ub = lam; else Lb = lam;
    const float newton = lam - f / (sp + 1e-12f);
    lam = (newton > Lb && newton < Ub) ? newton : 0.5f * (Lb + Ub);
  }

  // binned BCE + dice partials
  float tl = 0.0f, ti = 0.0f, tp = 0.0f;
#pragma unroll
  for (int j = 0; j < 8; ++j) {
    const float zs = zc[j] + lam;
    const float e = __expf(-fabsf(zs));
    const float lg = __logf(1.0f + e);
    const float mz = fmaxf(zs, 0.0f);
    const float sig = (zs >= 0.0f) ? (1.0f / (1.0f + e)) : (e / (1.0f + e));
    tl += cnt[j] * (mz + lg);
    ti += pb[j] * sig;
    tp += cnt[j] * sig;
  }
  tl = waveReduceSum(tl);
  ti = waveReduceSum(ti);
  tp = waveReduceSum(tp);
  if (lane == 0) {
    float* o = rowout + row * 4;
    o[0] = 4.0f * tl - (Szp + lam * Kh);  // block-weighted BCE row sum
    o[1] = ti;
    o[2] = tp;
    o[3] = Kh;
  }
}

// ---------------- K3: combine 256 rows into the two scalars -----------------
__global__ void final_kernel(const float* __restrict__ rowout, float* __restrict__ out) {
  const int t = threadIdx.x;               // 256 threads, 4 waves
  const float loss = rowout[t * 4 + 0];
  const float inter = rowout[t * 4 + 1];
  const float psum = rowout[t * 4 + 2];
  const float Kh = rowout[t * 4 + 3];
  float maskc = loss * (1.0f / (512.0f * 512.0f));
  float dicec = 1.0f - (2.0f * inter + 1.0f) / (4.0f * psum + Kh + 1.0f);
  maskc = waveReduceSum(maskc);
  dicec = waveReduceSum(dicec);
  __shared__ float red[8];
  const int wid = t >> 6, lane = t & 63;
  if (lane == 0) { red[wid] = maskc; red[4 + wid] = dicec; }
  __syncthreads();
  if (t == 0) {
    float a = 0.0f, b = 0.0f;
    for (int j = 0; j < 4; ++j) { a += red[j]; b += red[4 + j]; }
    out[0] = a / 256.0f;
    out[1] = b / 256.0f;
  }
}

// -------- fallback (round-2 style, 4 KB ws) in case ws is too small ---------
#define FB_TPB 1024
#define FB_NV4 (NCOLS / 4 / FB_TPB)
__device__ __forceinline__ void fbReduce2(float a, float b, float* red,
                                          int wid, int lane, float& A, float& B) {
  a = waveReduceSum(a);
  b = waveReduceSum(b);
  __syncthreads();
  if (lane == 0) { red[wid] = a; red[16 + wid] = b; }
  __syncthreads();
  float ta = 0.0f, tb = 0.0f;
#pragma unroll
  for (int j = 0; j < 16; ++j) { ta += red[j]; tb += red[16 + j]; }
  A = ta; B = tb;
}

__global__ __launch_bounds__(FB_TPB) void fb_row_kernel(
    const float* __restrict__ logits, const float* __restrict__ pos,
    float* __restrict__ rowout) {
  __shared__ unsigned int h_cnt[2048];
  __shared__ int h_sum[2048];
  __shared__ float red[64];
  const int row = blockIdx.x;
  const int tid = threadIdx.x, wid = tid >> 6, lane = tid & 63;
  const float4* z4 = (const float4*)(logits + (size_t)row * NCOLS);
  const float4* p4 = (const float4*)(pos + (size_t)row * NCOLS);
  for (int b = tid; b < 2048; b += FB_TPB) { h_cnt[b] = 0u; h_sum[b] = 0; }
  __syncthreads();
  const float invw = 2048.0f / 40.0f;
  float s_pos = 0.0f;
#pragma unroll
  for (int i = 0; i < FB_NV4; ++i) {
    float4 zv = z4[i * FB_TPB + tid];
    float4 pv = p4[i * FB_TPB + tid];
    s_pos += (pv.x + pv.y) + (pv.z + pv.w);
    float zz[4] = {zv.x, zv.y, zv.z, zv.w};
#pragma unroll
    for (int c = 0; c < 4; ++c) {
      int b = (int)((zz[c] + 20.0f) * invw);
      b = min(max(b, 0), 2047);
      atomicAdd(&h_cnt[b], 1u);
      atomicAdd(&h_sum[b], __float2int_rn(zz[c] * 1024.0f));
    }
  }
  float K_high, dummy;
  fbReduce2(s_pos, 0.0f, red, wid, lane, K_high, dummy);
  float K = fminf(fmaxf(K_high * 0.25f, 0.0f), (float)NCOLS);
  const float c0 = (float)h_cnt[tid];
  const float c1 = (float)h_cnt[tid + FB_TPB];
  const float zb0 = (c0 > 0.0f) ? (float)h_sum[tid] / (1024.0f * c0) : 0.0f;
  const float zb1 = (c1 > 0.0f) ? (float)h_sum[tid + FB_TPB] / (1024.0f * c1) : 0.0f;
  float Lb = -40.0f, Ub = 40.0f, lam = 0.0f;
  for (int it = 0; it < 40; ++it) {
    float p0 = 1.0f / (1.0f + __expf(-(zb0 + lam)));
    float p1 = 1.0f / (1.0f + __expf(-(zb1 + lam)));
    float F, S;
    fbReduce2(c0 * p0 + c1 * p1, c0 * p0 * (1.0f - p0) + c1 * p1 * (1.0f - p1),
              red, wid, lane, F, S);
    float f = F - K;
    if (fabsf(f) <= 1e-3f) break;
    if (f > 0.0f) Ub = lam; else Lb = lam;
    float newton = lam - f / (S + 1e-12f);
    lam = (newton > Lb && newton < Ub) ? newton : 0.5f * (Lb + Ub);
  }
  float loss = 0.0f, inter = 0.0f, psum = 0.0f;
#pragma unroll
  for (int i = 0; i < FB_NV4; ++i) {
    float4 zv = z4[i * FB_TPB + tid];
    float4 pv = p4[i * FB_TPB + tid];
    float zz[4] = {zv.x, zv.y, zv.z, zv.w};
    float pp[4] = {pv.x, pv.y, pv.z, pv.w};
#pragma unroll
    for (int c = 0; c < 4; ++c) {
      float zs = zz[c] + lam;
      float q = __expf(-fabsf(zs));
      loss += 4.0f * fmaxf(zs, 0.0f) - zs * pp[c] + 4.0f * __logf(1.0f + q);
      float sig = (zs >= 0.0f) ? (1.0f / (1.0f + q)) : (q / (1.0f + q));
      inter += sig * pp[c];
      psum += sig;
    }
  }
  float TL, TI;
  fbReduce2(loss, inter, red, wid, lane, TL, TI);
  float TP, d2;
  fbReduce2(psum, 0.0f, red, wid, lane, TP, d2);
  if (tid == 0) {
    float* o = rowout + row * 4;
    o[0] = TL; o[1] = TI; o[2] = TP; o[3] = K_high;
  }
}

extern "C" void kernel_launch(void* const* d_in, const int* in_sizes, int n_in,
                              void* d_out, int out_size, void* d_ws, size_t ws_size,
                              hipStream_t stream) {
  const float* logits = (const float*)d_in[0];
  const float* pos = (const float*)d_in[1];
  char* ws = (char*)d_ws;

  const size_t nblk = (size_t)MROWS * BPR;                  // 1024
  const size_t off_gh = 0;
  const size_t off_rowout = off_gh + nblk * NBINS * sizeof(unsigned int);
  const size_t needed = off_rowout + (size_t)MROWS * 4 * sizeof(float);

  if (ws_size >= needed) {
    unsigned int* gh = (unsigned int*)(ws + off_gh);
    float* rowout = (float*)(ws + off_rowout);
    hist_kernel<<<(int)nblk, K1_TPB, 0, stream>>>(logits, pos, gh);
    solve_kernel<<<MROWS, K2_TPB, 0, stream>>>(gh, rowout);
    final_kernel<<<1, 256, 0, stream>>>(rowout, (float*)d_out);
  } else {
    float* rowout = (float*)d_ws;          // 4 KB fallback path
    fb_row_kernel<<<MROWS, FB_TPB, 0, stream>>>(logits, pos, rowout);
    final_kernel<<<1, 256, 0, stream>>>(rowout, (float*)d_out);
  }
}